// Round 21
// baseline (136.260 us; speedup 1.0000x reference)
//
#include <hip/hip_runtime.h>
#include <hip/hip_bf16.h>
#include <cstdint>

#define BDIM 768
#define HN 12
#define HDIM 64
#define SEQ 2048
#define BATCH 4
#define MTOT (BATCH * SEQ)     // 8192

typedef __attribute__((ext_vector_type(8))) short bfrag;   // 8 bf16 (4 VGPR)
typedef __attribute__((ext_vector_type(4))) float f32x4;

union pfu { bfrag f; unsigned u[4]; };

static __device__ __forceinline__ unsigned short f2bf(float f) {
    union { float f; unsigned u; } v; v.f = f;
    unsigned r = v.u + 0x7FFF + ((v.u >> 16) & 1);   // RNE
    return (unsigned short)(r >> 16);
}

static __device__ __forceinline__ float fexp2(float x) {
    float r; asm("v_exp_f32 %0, %1" : "=v"(r) : "v"(x)); return r;
}

static __device__ __forceinline__ unsigned cvt_pk_bf16(float lo, float hi) {
    unsigned r;
    asm("v_cvt_pk_bf16_f32 %0, %1, %2" : "=v"(r) : "v"(lo), "v"(hi));
    return r;
}

// ---- cross-lane helpers: permlane swaps (VALU) with shfl fallback ----------
#if __has_builtin(__builtin_amdgcn_permlane32_swap) && __has_builtin(__builtin_amdgcn_permlane16_swap)
#define HAVE_PERMLANE 1
#else
#define HAVE_PERMLANE 0
#endif

static __device__ __forceinline__ float redmax16(float x) {
#if HAVE_PERMLANE
    union { float f; unsigned u; } a; a.f = x;
    auto r = __builtin_amdgcn_permlane16_swap(a.u, a.u, false, false);
    union { unsigned u; float f; } p, q; p.u = r[0]; q.u = r[1];
    return fmaxf(p.f, q.f);
#else
    return fmaxf(x, __shfl_xor(x, 16));
#endif
}

static __device__ __forceinline__ float redmax32(float x) {
#if HAVE_PERMLANE
    union { float f; unsigned u; } a; a.f = x;
    auto r = __builtin_amdgcn_permlane32_swap(a.u, a.u, false, false);
    union { unsigned u; float f; } p, q; p.u = r[0]; q.u = r[1];
    return fmaxf(p.f, q.f);
#else
    return fmaxf(x, __shfl_xor(x, 32));
#endif
}

// ---------------- prep (fused): x->bf16, w_qkv^T, w_proj^T ------------------
static __device__ void transpose_tile(
    const float* __restrict__ in, unsigned short* __restrict__ out,
    int R, int C, int cb, int rb, unsigned short (*t)[72])
{
    const int tid = threadIdx.x;
    const int c0 = cb * 64, r0 = rb * 64;
    #pragma unroll
    for (int i = 0; i < 4; ++i) {
        const int r = (tid >> 4) + i * 16;
        const int c = (tid & 15) * 4;
        const float4 v = *(const float4*)&in[(size_t)(r0 + r) * C + c0 + c];
        t[c + 0][r] = f2bf(v.x);
        t[c + 1][r] = f2bf(v.y);
        t[c + 2][r] = f2bf(v.z);
        t[c + 3][r] = f2bf(v.w);
    }
    __syncthreads();
    #pragma unroll
    for (int i = 0; i < 2; ++i) {
        const int c = (tid >> 3) + i * 32;
        const int r = (tid & 7) * 8;
        *(bfrag*)&out[(size_t)(c0 + c) * R + r0 + r] = *(const bfrag*)&t[c][r];
    }
}

// grid 3648: [0,3072) conv x; [3072,3504) w_qkv tiles; [3504,3648) w_proj.
__global__ __launch_bounds__(256) void prep_all(
    const float* __restrict__ x, unsigned short* __restrict__ xb,
    const float* __restrict__ w_qkv, unsigned short* __restrict__ wqT,
    const float* __restrict__ w_proj, unsigned short* __restrict__ wpT)
{
    __shared__ unsigned short t[64][72];
    const int bid = blockIdx.x;

    if (bid < 3072) {
        const int i = bid * 256 + threadIdx.x;
        const float4 a = ((const float4*)x)[i * 2];
        const float4 b = ((const float4*)x)[i * 2 + 1];
        bfrag o;
        o[0] = f2bf(a.x); o[1] = f2bf(a.y); o[2] = f2bf(a.z); o[3] = f2bf(a.w);
        o[4] = f2bf(b.x); o[5] = f2bf(b.y); o[6] = f2bf(b.z); o[7] = f2bf(b.w);
        ((bfrag*)xb)[i] = o;
    } else if (bid < 3504) {
        const int idx = bid - 3072;            // 432 tiles: (C/64=36, R/64=12)
        transpose_tile(w_qkv, wqT, BDIM, 3 * BDIM, idx % 36, idx / 36, t);
    } else {
        const int idx = bid - 3504;            // 144 tiles: (12, 12)
        transpose_tile(w_proj, wpT, BDIM, BDIM, idx % 12, idx / 12, t);
    }
}

// ---------------- GEMM1: qkv = x @ wqT^T + b, routed to qb/kb/vT ------------
// 128x192 tiles -> grid 12x64 = 768 blocks = 3/CU exact (no tail). 192 | 768
// so tiles never span the Q/K/V boundary.
#define VT_STRIDE 136   // elements; keeps b128 LDS rows 16B-aligned

__global__ __launch_bounds__(256) void gemm_qkv(
    const unsigned short* __restrict__ A,
    const unsigned short* __restrict__ Bt,
    const float* __restrict__ bias,
    unsigned short* __restrict__ qb,
    unsigned short* __restrict__ kb,
    unsigned short* __restrict__ vTt)
{
    __shared__ unsigned short Sh[192 * VT_STRIDE];   // staging alias + V-transpose
    unsigned short* As = Sh;                          // 128*64
    unsigned short* Bs = Sh + 128 * 64;               // 192*64

    const int tid  = threadIdx.x;
    const int lane = tid & 63;
    const int wid  = tid >> 6;
    const int l15  = lane & 15;
    const int l4   = lane >> 4;

    // bijective XCD swizzle (nwg = 12*64 = 768, 768 % 8 == 0)
    const int nwg  = (int)(gridDim.x * gridDim.y);
    const int flat = (int)(blockIdx.y * gridDim.x + blockIdx.x);
    const int swz  = (flat & 7) * (nwg >> 3) + (flat >> 3);
    const int m0 = (swz / (int)gridDim.x) * 128;
    const int n0 = (swz % (int)gridDim.x) * 192;

    const int wm = (wid >> 1) * 64;     // 2 m-halves of 64
    const int wn = (wid & 1) * 96;      // 2 n-halves of 96

    f32x4 acc[4][6] = {};

    for (int k0 = 0; k0 < BDIM; k0 += 64) {
        __syncthreads();
        #pragma unroll
        for (int i = 0; i < 4; ++i) {          // A: 128 rows
            const int row = wid * 32 + i * 8 + (lane >> 3);
            const int ck  = (((lane & 7) ^ (row & 7)) * 8);
            __builtin_amdgcn_global_load_lds(
                (const __attribute__((address_space(1))) void*)(A + (size_t)(m0 + row) * BDIM + k0 + ck),
                (__attribute__((address_space(3))) void*)(As + (wid * 32 + i * 8) * 64),
                16, 0, 0);
        }
        #pragma unroll
        for (int i = 0; i < 6; ++i) {          // B: 192 rows
            const int row = wid * 48 + i * 8 + (lane >> 3);
            const int ck  = (((lane & 7) ^ (row & 7)) * 8);
            __builtin_amdgcn_global_load_lds(
                (const __attribute__((address_space(1))) void*)(Bt + (size_t)(n0 + row) * BDIM + k0 + ck),
                (__attribute__((address_space(3))) void*)(Bs + (wid * 48 + i * 8) * 64),
                16, 0, 0);
        }
        __syncthreads();

        #pragma unroll
        for (int ks = 0; ks < 2; ++ks) {
            bfrag af[4], bfv[6];
            #pragma unroll
            for (int mi = 0; mi < 4; ++mi) {
                const int row = wm + mi * 16 + l15;
                const int ch  = (ks * 4 + l4) ^ (row & 7);
                af[mi] = *(const bfrag*)(As + row * 64 + ch * 8);
            }
            #pragma unroll
            for (int ni = 0; ni < 6; ++ni) {
                const int row = wn + ni * 16 + l15;
                const int ch  = (ks * 4 + l4) ^ (row & 7);
                bfv[ni] = *(const bfrag*)(Bs + row * 64 + ch * 8);
            }
            #pragma unroll
            for (int mi = 0; mi < 4; ++mi)
                #pragma unroll
                for (int ni = 0; ni < 6; ++ni)
                    acc[mi][ni] = __builtin_amdgcn_mfma_f32_16x16x32_bf16(
                        af[mi], bfv[ni], acc[mi][ni], 0, 0, 0);
        }
    }

    if (n0 < 1536) {
        // Q/K blocks (192-wide tiles never span the 768/1536 boundaries)
        unsigned short* dst = (n0 < 768) ? qb : kb;
        const int coff = (n0 < 768) ? 0 : 768;
        #pragma unroll
        for (int mi = 0; mi < 4; ++mi)
            #pragma unroll
            for (int ni = 0; ni < 6; ++ni) {
                const int n = n0 + wn + ni * 16 + l15;
                const float bv = bias[n];
                #pragma unroll
                for (int r = 0; r < 4; ++r) {
                    const int m = m0 + wm + mi * 16 + l4 * 4 + r;
                    dst[(size_t)m * BDIM + (n - coff)] = f2bf(acc[mi][ni][r] + bv);
                }
            }
    } else {
        // V block: transpose 128x192 tile through LDS -> coalesced stores
        __syncthreads();
        #pragma unroll
        for (int mi = 0; mi < 4; ++mi)
            #pragma unroll
            for (int ni = 0; ni < 6; ++ni) {
                const int n = n0 + wn + ni * 16 + l15;
                const float bv = bias[n];
                const int drow = wn + ni * 16 + l15;     // 0..191
                #pragma unroll
                for (int r = 0; r < 4; ++r) {
                    const int mcol = wm + mi * 16 + l4 * 4 + r;
                    Sh[drow * VT_STRIDE + mcol] = f2bf(acc[mi][ni][r] + bv);
                }
            }
        __syncthreads();
        // 192 d-rows x 128 s-cols: 3 passes, 4 threads/row x 32 cols each
        #pragma unroll
        for (int rr = 0; rr < 3; ++rr) {
            const int drow = rr * 64 + (tid >> 2);
            const int sc0  = (tid & 3) * 32;
            const size_t vrow = (size_t)(m0 >> 11) * 768 + (n0 - 1536) + drow;
            unsigned short* dp = vTt + vrow * SEQ + (m0 & (SEQ - 1)) + sc0;
            #pragma unroll
            for (int j = 0; j < 4; ++j)
                *(bfrag*)(dp + j * 8) = *(const bfrag*)(Sh + drow * VT_STRIDE + sc0 + j * 8);
        }
    }
}

// ---------------- GEMM2: out = yatt @ wpT^T + b (fp32 out), 64x128 tiles ----
__global__ __launch_bounds__(256) void gemm_proj(
    const unsigned short* __restrict__ A,   // [8192][768] bf16
    const unsigned short* __restrict__ Bt,  // [768][768] bf16
    const float* __restrict__ bias,
    float* __restrict__ C)
{
    __shared__ unsigned short As[64 * 64];
    __shared__ unsigned short Bs[128 * 64];

    const int tid  = threadIdx.x;
    const int lane = tid & 63;
    const int wid  = tid >> 6;
    const int l15  = lane & 15;
    const int l4   = lane >> 4;

    // bijective XCD swizzle (nwg = 6*128 = 768, 768 % 8 == 0)
    const int nwg  = (int)(gridDim.x * gridDim.y);
    const int flat = (int)(blockIdx.y * gridDim.x + blockIdx.x);
    const int swz  = (flat & 7) * (nwg >> 3) + (flat >> 3);
    const int m0 = (swz / (int)gridDim.x) * 64;
    const int n0 = (swz % (int)gridDim.x) * 128;

    const int wm = (wid >> 1) * 32;
    const int wn = (wid & 1) * 64;

    f32x4 acc[2][4] = {};

    for (int k0 = 0; k0 < BDIM; k0 += 64) {
        __syncthreads();
        #pragma unroll
        for (int i = 0; i < 2; ++i) {
            const int row = wid * 16 + i * 8 + (lane >> 3);
            const int ck  = (((lane & 7) ^ (row & 7)) * 8);
            __builtin_amdgcn_global_load_lds(
                (const __attribute__((address_space(1))) void*)(A + (size_t)(m0 + row) * BDIM + k0 + ck),
                (__attribute__((address_space(3))) void*)(As + (wid * 16 + i * 8) * 64),
                16, 0, 0);
        }
        #pragma unroll
        for (int i = 0; i < 4; ++i) {
            const int row = wid * 32 + i * 8 + (lane >> 3);
            const int ck  = (((lane & 7) ^ (row & 7)) * 8);
            __builtin_amdgcn_global_load_lds(
                (const __attribute__((address_space(1))) void*)(Bt + (size_t)(n0 + row) * BDIM + k0 + ck),
                (__attribute__((address_space(3))) void*)(Bs + (wid * 32 + i * 8) * 64),
                16, 0, 0);
        }
        __syncthreads();

        #pragma unroll
        for (int ks = 0; ks < 2; ++ks) {
            bfrag af[2], bfv[4];
            #pragma unroll
            for (int mi = 0; mi < 2; ++mi) {
                const int row = wm + mi * 16 + l15;
                const int ch  = (ks * 4 + l4) ^ (row & 7);
                af[mi] = *(const bfrag*)(As + row * 64 + ch * 8);
            }
            #pragma unroll
            for (int ni = 0; ni < 4; ++ni) {
                const int row = wn + ni * 16 + l15;
                const int ch  = (ks * 4 + l4) ^ (row & 7);
                bfv[ni] = *(const bfrag*)(Bs + row * 64 + ch * 8);
            }
            #pragma unroll
            for (int mi = 0; mi < 2; ++mi)
                #pragma unroll
                for (int ni = 0; ni < 4; ++ni)
                    acc[mi][ni] = __builtin_amdgcn_mfma_f32_16x16x32_bf16(
                        af[mi], bfv[ni], acc[mi][ni], 0, 0, 0);
        }
    }

    #pragma unroll
    for (int mi = 0; mi < 2; ++mi)
        #pragma unroll
        for (int ni = 0; ni < 4; ++ni) {
            const int n = n0 + wn + ni * 16 + l15;
            const float bv = bias[n];
            #pragma unroll
            for (int r = 0; r < 4; ++r) {
                const int m = m0 + wm + mi * 16 + l4 * 4 + r;
                C[(size_t)m * BDIM + n] = acc[mi][ni][r] + bv;
            }
        }
}

// ---------------- MFMA flash attention: single-q, 768 uniform static items --
// Item = (bh, j): segment A = q-tile j (j+1 K-steps), segment B = q-tile 31-j
// (32-j steps) -> 33 uniform steps. Grid 768 = 3 blocks/CU sustained, no queue.
#define C2 0.18033688011112042f   /* 0.125 * log2(e) */
#define THR 8.0f

__global__ __launch_bounds__(256, 2) void attn_flash_mfma(
    const unsigned short* __restrict__ qb,
    const unsigned short* __restrict__ kb,
    const unsigned short* __restrict__ vT,
    unsigned short* __restrict__ yatt)
{
    __shared__ unsigned short Ks[2][64 * 64];   // [k][d] swizzled
    __shared__ unsigned short Vs[2][64 * 64];   // [d][k] swizzled

    const int bid  = blockIdx.x;
    const int hint = bid & 7;            // XCD slot
    const int idx  = bid >> 3;           // 0..95
    const int bh   = hint * 6 + idx % 6;
    const int jj   = idx / 6;            // 0..15
    const int h = bh % HN, b = bh / HN;

    const int tid  = threadIdx.x;
    const int lane = tid & 63;
    const int wid  = tid >> 6;
    const int l15  = lane & 15;
    const int l4   = lane >> 4;

    bfrag onesf;
    #pragma unroll
    for (int j = 0; j < 8; ++j) onesf[j] = (short)0x3F80;   // bf16 1.0

    const unsigned short* kg = kb + (size_t)b * SEQ * BDIM + h * HDIM;
    const unsigned short* vg = vT + (size_t)bh * HDIM * SEQ;

    auto stage = [&](int bufi, int ktile) {
        const int k0 = ktile * 64;
        #pragma unroll
        for (int i = 0; i < 2; ++i) {
            const int row = wid * 16 + i * 8 + (lane >> 3);
            const int ck  = ((lane & 7) ^ (row & 7)) * 8;
            __builtin_amdgcn_global_load_lds(
                (const __attribute__((address_space(1))) void*)(kg + (size_t)(k0 + row) * BDIM + ck),
                (__attribute__((address_space(3))) void*)(&Ks[bufi][(wid * 16 + i * 8) * 64]),
                16, 0, 0);
            __builtin_amdgcn_global_load_lds(
                (const __attribute__((address_space(1))) void*)(vg + (size_t)row * SEQ + k0 + ck),
                (__attribute__((address_space(3))) void*)(&Vs[bufi][(wid * 16 + i * 8) * 64]),
                16, 0, 0);
        }
    };

    #pragma unroll 1
    for (int seg = 0; seg < 2; ++seg) {
        const int qt = seg ? (31 - jj) : jj;
        const int q0 = qt * 64;
        const int ktmax = qt;

        // Q fragments (B-operand): Q[q = q0+wid*16+l15][d chunks]
        const unsigned short* qr0 =
            qb + (size_t)(b * SEQ + q0 + wid * 16 + l15) * BDIM + h * HDIM;
        const bfrag qf0 = *(const bfrag*)(qr0 + l4 * 8);
        const bfrag qf1 = *(const bfrag*)(qr0 + 32 + l4 * 8);

        f32x4 acc[4] = {};
        f32x4 accl   = {};
        float m = -3.0e38f;

        pfu pf[2];
        bfrag vr[2][4];
        #pragma unroll
        for (int ks = 0; ks < 2; ++ks) {
            #pragma unroll
            for (int i = 0; i < 4; ++i) pf[ks].u[i] = 0u;
            #pragma unroll
            for (int ds = 0; ds < 4; ++ds)
                #pragma unroll
                for (int j = 0; j < 8; ++j) vr[ks][ds][j] = 0;
        }

        // softmax: tree-max, defer-max rescale, exp, P-dance.
        auto softmax_dance = [&](f32x4* s) {
            float t0 = fmaxf(s[0][0], s[0][1]);
            float t1 = fmaxf(s[0][2], s[0][3]);
            float t2 = fmaxf(s[1][0], s[1][1]);
            float t3 = fmaxf(s[1][2], s[1][3]);
            float t4 = fmaxf(s[2][0], s[2][1]);
            float t5 = fmaxf(s[2][2], s[2][3]);
            float t6 = fmaxf(s[3][0], s[3][1]);
            float t7 = fmaxf(s[3][2], s[3][3]);
            t0 = fmaxf(t0, t1); t2 = fmaxf(t2, t3);
            t4 = fmaxf(t4, t5); t6 = fmaxf(t6, t7);
            t0 = fmaxf(t0, t2); t4 = fmaxf(t4, t6);
            float mx = fmaxf(t0, t4);
            mx = redmax16(mx);
            mx = redmax32(mx);
            const float mx2 = mx * C2;

            if (!__all(mx2 <= m + THR)) {
                const float mnew = fmaxf(m, mx2);
                const float fac  = fexp2(m - mnew);
                m = mnew;
                #pragma unroll
                for (int r = 0; r < 4; ++r) {
                    const float fr = __shfl(fac, (lane & 48) | (l4 * 4 + r));
                    #pragma unroll
                    for (int ds = 0; ds < 4; ++ds) acc[ds][r] *= fr;
                    accl[r] *= fr;
                }
            }

            #pragma unroll
            for (int cs = 0; cs < 4; ++cs)
                #pragma unroll
                for (int r = 0; r < 4; ++r)
                    s[cs][r] = fexp2(fmaf(s[cs][r], C2, -m));

            unsigned pk[4][2];
            #pragma unroll
            for (int cs = 0; cs < 4; ++cs) {
                pk[cs][0] = cvt_pk_bf16(s[cs][0], s[cs][1]);
                pk[cs][1] = cvt_pk_bf16(s[cs][2], s[cs][3]);
            }
            #pragma unroll
            for (int ks = 0; ks < 2; ++ks)
                #pragma unroll
                for (int i = 0; i < 2; ++i) {
#if HAVE_PERMLANE
                    auto r1 = __builtin_amdgcn_permlane32_swap(
                        pk[ks * 2][i], pk[ks * 2 + 1][i], false, false);
                    auto r2 = __builtin_amdgcn_permlane16_swap(r1[0], r1[1], false, false);
                    pf[ks].u[i]     = r2[0];
                    pf[ks].u[2 + i] = r2[1];
#else
                    const unsigned A  = pk[ks * 2][i];
                    const unsigned B  = pk[ks * 2 + 1][i];
                    const unsigned Ax = __shfl_xor(A, 32);
                    const unsigned Bx = __shfl_xor(B, 32);
                    const unsigned P1 = (l4 < 2) ? A : Bx;
                    const unsigned P2 = (l4 < 2) ? Ax : B;
                    const unsigned S1 = __shfl_xor(P1, 16);
                    const unsigned S2 = __shfl_xor(P2, 16);
                    pf[ks].u[i]     = (l4 & 1) ? S2 : P1;
                    pf[ks].u[2 + i] = (l4 & 1) ? P2 : S1;
#endif
                }
        };

        __syncthreads();          // protect K/V buffers from previous segment
        stage(0, 0);
        __syncthreads();

        int buf = 0;
        for (int kt = 0;;) {
            if (kt < ktmax) stage(buf ^ 1, kt + 1);   // async prefetch

            const unsigned short* Kb = Ks[buf];
            const unsigned short* Vb = Vs[buf];

            // ---- MFMA cluster: QK(kt) + deferred PV/rowsum(kt-1) ----
            f32x4 s[4] = {};
            __builtin_amdgcn_s_setprio(1);
            #pragma unroll
            for (int ks = 0; ks < 2; ++ks) {
                const bfrag qk = ks ? qf1 : qf0;
                #pragma unroll
                for (int cs = 0; cs < 4; ++cs) {
                    const int row = cs * 16 + l15;
                    const int ch  = (ks * 4 + l4) ^ (row & 7);
                    const bfrag kf = *(const bfrag*)(Kb + row * 64 + ch * 8);
                    s[cs] = __builtin_amdgcn_mfma_f32_16x16x32_bf16(kf, qk, s[cs], 0, 0, 0);
                }
            }
            #pragma unroll
            for (int ks = 0; ks < 2; ++ks) {
                #pragma unroll
                for (int ds = 0; ds < 4; ++ds)
                    acc[ds] = __builtin_amdgcn_mfma_f32_16x16x32_bf16(
                        pf[ks].f, vr[ks][ds], acc[ds], 0, 0, 0);
                accl = __builtin_amdgcn_mfma_f32_16x16x32_bf16(pf[ks].f, onesf, accl, 0, 0, 0);
            }
            __builtin_amdgcn_s_setprio(0);

            // ---- refill V regs with tile kt ----
            #pragma unroll
            for (int ks = 0; ks < 2; ++ks)
                #pragma unroll
                for (int ds = 0; ds < 4; ++ds) {
                    const int vrow = ds * 16 + l15;
                    const int vch  = (ks * 4 + l4) ^ (vrow & 7);
                    vr[ks][ds] = *(const bfrag*)(Vb + vrow * 64 + vch * 8);
                }

            // ---- causal mask on diagonal tile (k > q) ----
            if (kt == ktmax) {
                #pragma unroll
                for (int cs = 0; cs < 4; ++cs)
                    #pragma unroll
                    for (int r = 0; r < 4; ++r)
                        if (cs * 16 + l4 * 4 + r > wid * 16 + l15)
                            s[cs][r] = -3.0e38f;
            }

            softmax_dance(s);

            if (kt == ktmax) break;
            __syncthreads();      // drains own gload_lds + all waves done
            buf ^= 1; ++kt;
        }

        // ---- epilogue: deferred PV + rowsum of final tile ----
        #pragma unroll
        for (int ks = 0; ks < 2; ++ks) {
            #pragma unroll
            for (int ds = 0; ds < 4; ++ds)
                acc[ds] = __builtin_amdgcn_mfma_f32_16x16x32_bf16(
                    pf[ks].f, vr[ks][ds], acc[ds], 0, 0, 0);
            accl = __builtin_amdgcn_mfma_f32_16x16x32_bf16(pf[ks].f, onesf, accl, 0, 0, 0);
        }

        // ---- normalize + store (accl rows match acc rows) ----
        #pragma unroll
        for (int r = 0; r < 4; ++r) {
            const float iv = 1.f / accl[r];
            unsigned short* o =
                yatt + (size_t)(b * SEQ + q0 + wid * 16 + l4 * 4 + r) * BDIM + h * HDIM;
            #pragma unroll
            for (int ds = 0; ds < 4; ++ds)
                o[ds * 16 + l15] = f2bf(acc[ds][r] * iv);
        }
    }
}

// ---------------- launch -----------------------------------------------------
extern "C" void kernel_launch(void* const* d_in, const int* in_sizes, int n_in,
                              void* d_out, int out_size, void* d_ws, size_t ws_size,
                              hipStream_t stream)
{
    const float* x      = (const float*)d_in[0];
    const float* w_qkv  = (const float*)d_in[1];
    const float* b_qkv  = (const float*)d_in[2];
    const float* w_proj = (const float*)d_in[3];
    const float* b_proj = (const float*)d_in[4];
    float* out = (float*)d_out;

    unsigned short* xb   = (unsigned short*)d_ws;                 // [8192][768]
    unsigned short* qb   = xb  + (size_t)MTOT * BDIM;             // [8192][768]
    unsigned short* kbuf = qb  + (size_t)MTOT * BDIM;             // [8192][768]
    unsigned short* vT   = kbuf + (size_t)MTOT * BDIM;            // [4*768][2048]
    unsigned short* yatt = vT  + (size_t)MTOT * BDIM;             // [8192][768]
    unsigned short* wqT  = yatt + (size_t)MTOT * BDIM;            // [2304][768]
    unsigned short* wpT  = wqT + (size_t)3 * BDIM * BDIM;         // [768][768]

    // fused prep (x conv + both weight transposes)
    prep_all<<<dim3(3648), 256, 0, stream>>>(
        x, xb, w_qkv, wqT, w_proj, wpT);

    // qkv GEMM, 128x192 tiles (768 blocks = 3/CU exact)
    gemm_qkv<<<dim3(12, 64), 256, 0, stream>>>(
        xb, wqT, b_qkv, qb, kbuf, vT);

    // flash attention (768 uniform static causal-paired items, 3 blocks/CU)
    attn_flash_mfma<<<dim3(768), 256, 0, stream>>>(qb, kbuf, vT, yatt);

    // out = yatt @ w_proj + b_proj   (fp32 out, 64x128 tiles)
    gemm_proj<<<dim3(BDIM / 128, MTOT / 64), 256, 0, stream>>>(
        yatt, wpT, b_proj, out);
}

// Round 22
// 116.002 us; speedup vs baseline: 1.1746x; 1.1746x over previous
//
#include <hip/hip_runtime.h>
#include <hip/hip_bf16.h>
#include <cstdint>

#define BDIM 768
#define HN 12
#define HDIM 64
#define SEQ 2048
#define BATCH 4
#define MTOT (BATCH * SEQ)     // 8192

typedef __attribute__((ext_vector_type(8))) short bfrag;   // 8 bf16 (4 VGPR)
typedef __attribute__((ext_vector_type(4))) float f32x4;

union pfu { bfrag f; unsigned u[4]; };

static __device__ __forceinline__ unsigned short f2bf(float f) {
    union { float f; unsigned u; } v; v.f = f;
    unsigned r = v.u + 0x7FFF + ((v.u >> 16) & 1);   // RNE
    return (unsigned short)(r >> 16);
}

static __device__ __forceinline__ float fexp2(float x) {
    float r; asm("v_exp_f32 %0, %1" : "=v"(r) : "v"(x)); return r;
}

static __device__ __forceinline__ unsigned cvt_pk_bf16(float lo, float hi) {
    unsigned r;
    asm("v_cvt_pk_bf16_f32 %0, %1, %2" : "=v"(r) : "v"(lo), "v"(hi));
    return r;
}

// ---- cross-lane helpers: permlane swaps (VALU) with shfl fallback ----------
#if __has_builtin(__builtin_amdgcn_permlane32_swap) && __has_builtin(__builtin_amdgcn_permlane16_swap)
#define HAVE_PERMLANE 1
#else
#define HAVE_PERMLANE 0
#endif

static __device__ __forceinline__ float redmax16(float x) {
#if HAVE_PERMLANE
    union { float f; unsigned u; } a; a.f = x;
    auto r = __builtin_amdgcn_permlane16_swap(a.u, a.u, false, false);
    union { unsigned u; float f; } p, q; p.u = r[0]; q.u = r[1];
    return fmaxf(p.f, q.f);
#else
    return fmaxf(x, __shfl_xor(x, 16));
#endif
}

static __device__ __forceinline__ float redmax32(float x) {
#if HAVE_PERMLANE
    union { float f; unsigned u; } a; a.f = x;
    auto r = __builtin_amdgcn_permlane32_swap(a.u, a.u, false, false);
    union { unsigned u; float f; } p, q; p.u = r[0]; q.u = r[1];
    return fmaxf(p.f, q.f);
#else
    return fmaxf(x, __shfl_xor(x, 32));
#endif
}

// ---------------- prep (fused): x->bf16, w_qkv^T, w_proj^T ------------------
static __device__ void transpose_tile(
    const float* __restrict__ in, unsigned short* __restrict__ out,
    int R, int C, int cb, int rb, unsigned short (*t)[72])
{
    const int tid = threadIdx.x;
    const int c0 = cb * 64, r0 = rb * 64;
    #pragma unroll
    for (int i = 0; i < 4; ++i) {
        const int r = (tid >> 4) + i * 16;
        const int c = (tid & 15) * 4;
        const float4 v = *(const float4*)&in[(size_t)(r0 + r) * C + c0 + c];
        t[c + 0][r] = f2bf(v.x);
        t[c + 1][r] = f2bf(v.y);
        t[c + 2][r] = f2bf(v.z);
        t[c + 3][r] = f2bf(v.w);
    }
    __syncthreads();
    #pragma unroll
    for (int i = 0; i < 2; ++i) {
        const int c = (tid >> 3) + i * 32;
        const int r = (tid & 7) * 8;
        *(bfrag*)&out[(size_t)(c0 + c) * R + r0 + r] = *(const bfrag*)&t[c][r];
    }
}

// grid 3648: [0,3072) conv x; [3072,3504) w_qkv tiles; [3504,3648) w_proj.
__global__ __launch_bounds__(256) void prep_all(
    const float* __restrict__ x, unsigned short* __restrict__ xb,
    const float* __restrict__ w_qkv, unsigned short* __restrict__ wqT,
    const float* __restrict__ w_proj, unsigned short* __restrict__ wpT)
{
    __shared__ unsigned short t[64][72];
    const int bid = blockIdx.x;

    if (bid < 3072) {
        const int i = bid * 256 + threadIdx.x;
        const float4 a = ((const float4*)x)[i * 2];
        const float4 b = ((const float4*)x)[i * 2 + 1];
        bfrag o;
        o[0] = f2bf(a.x); o[1] = f2bf(a.y); o[2] = f2bf(a.z); o[3] = f2bf(a.w);
        o[4] = f2bf(b.x); o[5] = f2bf(b.y); o[6] = f2bf(b.z); o[7] = f2bf(b.w);
        ((bfrag*)xb)[i] = o;
    } else if (bid < 3504) {
        const int idx = bid - 3072;            // 432 tiles: (C/64=36, R/64=12)
        transpose_tile(w_qkv, wqT, BDIM, 3 * BDIM, idx % 36, idx / 36, t);
    } else {
        const int idx = bid - 3504;            // 144 tiles: (12, 12)
        transpose_tile(w_proj, wpT, BDIM, BDIM, idx % 12, idx / 12, t);
    }
}

// ---------------- GEMM1: qkv = x @ wqT^T + b, 64x128 tiles ------------------
// grid (18, 128) = 2304 blocks; 128-wide N-tiles land exactly on the Q/K/V
// boundaries (768, 1536) so routing stays block-uniform. V-blocks transpose
// through LDS (stride 72) and store coalesced along s.
#define TR_STRIDE 72

__global__ __launch_bounds__(256) void gemm_qkv(
    const unsigned short* __restrict__ A,
    const unsigned short* __restrict__ Bt,
    const float* __restrict__ bias,
    unsigned short* __restrict__ qb,
    unsigned short* __restrict__ kb,
    unsigned short* __restrict__ vTt)
{
    __shared__ unsigned short Sh[64 * 64 + 128 * 64];   // As|Bs; V-transpose alias
    unsigned short* As = Sh;
    unsigned short* Bs = Sh + 64 * 64;

    const int tid  = threadIdx.x;
    const int lane = tid & 63;
    const int wid  = tid >> 6;
    const int l15  = lane & 15;
    const int l4   = lane >> 4;

    // bijective XCD swizzle (nwg = 18*128 = 2304, 2304 % 8 == 0)
    const int nwg  = (int)(gridDim.x * gridDim.y);
    const int flat = (int)(blockIdx.y * gridDim.x + blockIdx.x);
    const int swz  = (flat & 7) * (nwg >> 3) + (flat >> 3);
    const int m0 = (swz / (int)gridDim.x) * 64;
    const int n0 = (swz % (int)gridDim.x) * 128;

    const int wm = (wid >> 1) * 32;    // 2 m-sub of 32 rows
    const int wn = (wid & 1) * 64;

    f32x4 acc[2][4] = {};

    for (int k0 = 0; k0 < BDIM; k0 += 64) {
        __syncthreads();
        #pragma unroll
        for (int i = 0; i < 2; ++i) {   // A: 64 rows
            const int row = wid * 16 + i * 8 + (lane >> 3);
            const int ck  = (((lane & 7) ^ (row & 7)) * 8);
            __builtin_amdgcn_global_load_lds(
                (const __attribute__((address_space(1))) void*)(A + (size_t)(m0 + row) * BDIM + k0 + ck),
                (__attribute__((address_space(3))) void*)(As + (wid * 16 + i * 8) * 64),
                16, 0, 0);
        }
        #pragma unroll
        for (int i = 0; i < 4; ++i) {   // B: 128 rows
            const int row = wid * 32 + i * 8 + (lane >> 3);
            const int ck  = (((lane & 7) ^ (row & 7)) * 8);
            __builtin_amdgcn_global_load_lds(
                (const __attribute__((address_space(1))) void*)(Bt + (size_t)(n0 + row) * BDIM + k0 + ck),
                (__attribute__((address_space(3))) void*)(Bs + (wid * 32 + i * 8) * 64),
                16, 0, 0);
        }
        __syncthreads();

        #pragma unroll
        for (int ks = 0; ks < 2; ++ks) {
            bfrag af[2], bfv[4];
            #pragma unroll
            for (int mi = 0; mi < 2; ++mi) {
                const int row = wm + mi * 16 + l15;
                const int ch  = (ks * 4 + l4) ^ (row & 7);
                af[mi] = *(const bfrag*)(As + row * 64 + ch * 8);
            }
            #pragma unroll
            for (int ni = 0; ni < 4; ++ni) {
                const int row = wn + ni * 16 + l15;
                const int ch  = (ks * 4 + l4) ^ (row & 7);
                bfv[ni] = *(const bfrag*)(Bs + row * 64 + ch * 8);
            }
            #pragma unroll
            for (int mi = 0; mi < 2; ++mi)
                #pragma unroll
                for (int ni = 0; ni < 4; ++ni)
                    acc[mi][ni] = __builtin_amdgcn_mfma_f32_16x16x32_bf16(
                        af[mi], bfv[ni], acc[mi][ni], 0, 0, 0);
        }
    }

    if (n0 < 1536) {
        // Q/K blocks (block-uniform: 128 | 768)
        unsigned short* dst = (n0 < 768) ? qb : kb;
        const int coff = (n0 < 768) ? 0 : 768;
        #pragma unroll
        for (int mi = 0; mi < 2; ++mi)
            #pragma unroll
            for (int ni = 0; ni < 4; ++ni) {
                const int n = n0 + wn + ni * 16 + l15;
                const float bv = bias[n];
                #pragma unroll
                for (int r = 0; r < 4; ++r) {
                    const int m = m0 + wm + mi * 16 + l4 * 4 + r;
                    dst[(size_t)m * BDIM + (n - coff)] = f2bf(acc[mi][ni][r] + bv);
                }
            }
    } else {
        // V block: transpose 64x128 tile through LDS -> coalesced stores
        __syncthreads();
        #pragma unroll
        for (int mi = 0; mi < 2; ++mi)
            #pragma unroll
            for (int ni = 0; ni < 4; ++ni) {
                const int n = n0 + wn + ni * 16 + l15;
                const float bv = bias[n];
                const int drow = wn + ni * 16 + l15;     // 0..127
                #pragma unroll
                for (int r = 0; r < 4; ++r) {
                    const int mcol = wm + mi * 16 + l4 * 4 + r;   // 0..63
                    Sh[drow * TR_STRIDE + mcol] = f2bf(acc[mi][ni][r] + bv);
                }
            }
        __syncthreads();
        // 128 d-rows x 64 s-cols: 2 threads/row x 32 cols each
        const int drow = tid >> 1;
        const int sc0  = (tid & 1) * 32;
        const size_t vrow = (size_t)(m0 >> 11) * 768 + (n0 - 1536) + drow;
        unsigned short* dp = vTt + vrow * SEQ + (m0 & (SEQ - 1)) + sc0;
        #pragma unroll
        for (int j = 0; j < 4; ++j)
            *(bfrag*)(dp + j * 8) = *(const bfrag*)(Sh + drow * TR_STRIDE + sc0 + j * 8);
    }
}

// ---------------- GEMM2: out = yatt @ wpT^T + b (fp32 out), 64x128 tiles ----
__global__ __launch_bounds__(256) void gemm_proj(
    const unsigned short* __restrict__ A,   // [8192][768] bf16
    const unsigned short* __restrict__ Bt,  // [768][768] bf16
    const float* __restrict__ bias,
    float* __restrict__ C)
{
    __shared__ unsigned short As[64 * 64];
    __shared__ unsigned short Bs[128 * 64];

    const int tid  = threadIdx.x;
    const int lane = tid & 63;
    const int wid  = tid >> 6;
    const int l15  = lane & 15;
    const int l4   = lane >> 4;

    // bijective XCD swizzle (nwg = 6*128 = 768, 768 % 8 == 0)
    const int nwg  = (int)(gridDim.x * gridDim.y);
    const int flat = (int)(blockIdx.y * gridDim.x + blockIdx.x);
    const int swz  = (flat & 7) * (nwg >> 3) + (flat >> 3);
    const int m0 = (swz / (int)gridDim.x) * 64;
    const int n0 = (swz % (int)gridDim.x) * 128;

    const int wm = (wid >> 1) * 32;
    const int wn = (wid & 1) * 64;

    f32x4 acc[2][4] = {};

    for (int k0 = 0; k0 < BDIM; k0 += 64) {
        __syncthreads();
        #pragma unroll
        for (int i = 0; i < 2; ++i) {
            const int row = wid * 16 + i * 8 + (lane >> 3);
            const int ck  = (((lane & 7) ^ (row & 7)) * 8);
            __builtin_amdgcn_global_load_lds(
                (const __attribute__((address_space(1))) void*)(A + (size_t)(m0 + row) * BDIM + k0 + ck),
                (__attribute__((address_space(3))) void*)(As + (wid * 16 + i * 8) * 64),
                16, 0, 0);
        }
        #pragma unroll
        for (int i = 0; i < 4; ++i) {
            const int row = wid * 32 + i * 8 + (lane >> 3);
            const int ck  = (((lane & 7) ^ (row & 7)) * 8);
            __builtin_amdgcn_global_load_lds(
                (const __attribute__((address_space(1))) void*)(Bt + (size_t)(n0 + row) * BDIM + k0 + ck),
                (__attribute__((address_space(3))) void*)(Bs + (wid * 32 + i * 8) * 64),
                16, 0, 0);
        }
        __syncthreads();

        #pragma unroll
        for (int ks = 0; ks < 2; ++ks) {
            bfrag af[2], bfv[4];
            #pragma unroll
            for (int mi = 0; mi < 2; ++mi) {
                const int row = wm + mi * 16 + l15;
                const int ch  = (ks * 4 + l4) ^ (row & 7);
                af[mi] = *(const bfrag*)(As + row * 64 + ch * 8);
            }
            #pragma unroll
            for (int ni = 0; ni < 4; ++ni) {
                const int row = wn + ni * 16 + l15;
                const int ch  = (ks * 4 + l4) ^ (row & 7);
                bfv[ni] = *(const bfrag*)(Bs + row * 64 + ch * 8);
            }
            #pragma unroll
            for (int mi = 0; mi < 2; ++mi)
                #pragma unroll
                for (int ni = 0; ni < 4; ++ni)
                    acc[mi][ni] = __builtin_amdgcn_mfma_f32_16x16x32_bf16(
                        af[mi], bfv[ni], acc[mi][ni], 0, 0, 0);
        }
    }

    #pragma unroll
    for (int mi = 0; mi < 2; ++mi)
        #pragma unroll
        for (int ni = 0; ni < 4; ++ni) {
            const int n = n0 + wn + ni * 16 + l15;
            const float bv = bias[n];
            #pragma unroll
            for (int r = 0; r < 4; ++r) {
                const int m = m0 + wm + mi * 16 + l4 * 4 + r;
                C[(size_t)m * BDIM + n] = acc[mi][ni][r] + bv;
            }
        }
}

// ---------------- MFMA flash attention: single-q, 768 uniform static items --
// Item = (bh, j): segment A = q-tile j (j+1 K-steps), segment B = q-tile 31-j
// (32-j steps) -> 33 uniform steps. Grid 768 = 3 blocks/CU sustained, no queue.
#define C2 0.18033688011112042f   /* 0.125 * log2(e) */
#define THR 8.0f

__global__ __launch_bounds__(256, 2) void attn_flash_mfma(
    const unsigned short* __restrict__ qb,
    const unsigned short* __restrict__ kb,
    const unsigned short* __restrict__ vT,
    unsigned short* __restrict__ yatt)
{
    __shared__ unsigned short Ks[2][64 * 64];   // [k][d] swizzled
    __shared__ unsigned short Vs[2][64 * 64];   // [d][k] swizzled

    const int bid  = blockIdx.x;
    const int hint = bid & 7;            // XCD slot
    const int idx  = bid >> 3;           // 0..95
    const int bh   = hint * 6 + idx % 6;
    const int jj   = idx / 6;            // 0..15
    const int h = bh % HN, b = bh / HN;

    const int tid  = threadIdx.x;
    const int lane = tid & 63;
    const int wid  = tid >> 6;
    const int l15  = lane & 15;
    const int l4   = lane >> 4;

    bfrag onesf;
    #pragma unroll
    for (int j = 0; j < 8; ++j) onesf[j] = (short)0x3F80;   // bf16 1.0

    const unsigned short* kg = kb + (size_t)b * SEQ * BDIM + h * HDIM;
    const unsigned short* vg = vT + (size_t)bh * HDIM * SEQ;

    auto stage = [&](int bufi, int ktile) {
        const int k0 = ktile * 64;
        #pragma unroll
        for (int i = 0; i < 2; ++i) {
            const int row = wid * 16 + i * 8 + (lane >> 3);
            const int ck  = ((lane & 7) ^ (row & 7)) * 8;
            __builtin_amdgcn_global_load_lds(
                (const __attribute__((address_space(1))) void*)(kg + (size_t)(k0 + row) * BDIM + ck),
                (__attribute__((address_space(3))) void*)(&Ks[bufi][(wid * 16 + i * 8) * 64]),
                16, 0, 0);
            __builtin_amdgcn_global_load_lds(
                (const __attribute__((address_space(1))) void*)(vg + (size_t)row * SEQ + k0 + ck),
                (__attribute__((address_space(3))) void*)(&Vs[bufi][(wid * 16 + i * 8) * 64]),
                16, 0, 0);
        }
    };

    #pragma unroll 1
    for (int seg = 0; seg < 2; ++seg) {
        const int qt = seg ? (31 - jj) : jj;
        const int q0 = qt * 64;
        const int ktmax = qt;

        // Q fragments (B-operand): Q[q = q0+wid*16+l15][d chunks]
        const unsigned short* qr0 =
            qb + (size_t)(b * SEQ + q0 + wid * 16 + l15) * BDIM + h * HDIM;
        const bfrag qf0 = *(const bfrag*)(qr0 + l4 * 8);
        const bfrag qf1 = *(const bfrag*)(qr0 + 32 + l4 * 8);

        f32x4 acc[4] = {};
        f32x4 accl   = {};
        float m = -3.0e38f;

        pfu pf[2];
        bfrag vr[2][4];
        #pragma unroll
        for (int ks = 0; ks < 2; ++ks) {
            #pragma unroll
            for (int i = 0; i < 4; ++i) pf[ks].u[i] = 0u;
            #pragma unroll
            for (int ds = 0; ds < 4; ++ds)
                #pragma unroll
                for (int j = 0; j < 8; ++j) vr[ks][ds][j] = 0;
        }

        // softmax: tree-max, defer-max rescale, exp, P-dance.
        auto softmax_dance = [&](f32x4* s) {
            float t0 = fmaxf(s[0][0], s[0][1]);
            float t1 = fmaxf(s[0][2], s[0][3]);
            float t2 = fmaxf(s[1][0], s[1][1]);
            float t3 = fmaxf(s[1][2], s[1][3]);
            float t4 = fmaxf(s[2][0], s[2][1]);
            float t5 = fmaxf(s[2][2], s[2][3]);
            float t6 = fmaxf(s[3][0], s[3][1]);
            float t7 = fmaxf(s[3][2], s[3][3]);
            t0 = fmaxf(t0, t1); t2 = fmaxf(t2, t3);
            t4 = fmaxf(t4, t5); t6 = fmaxf(t6, t7);
            t0 = fmaxf(t0, t2); t4 = fmaxf(t4, t6);
            float mx = fmaxf(t0, t4);
            mx = redmax16(mx);
            mx = redmax32(mx);
            const float mx2 = mx * C2;

            if (!__all(mx2 <= m + THR)) {
                const float mnew = fmaxf(m, mx2);
                const float fac  = fexp2(m - mnew);
                m = mnew;
                #pragma unroll
                for (int r = 0; r < 4; ++r) {
                    const float fr = __shfl(fac, (lane & 48) | (l4 * 4 + r));
                    #pragma unroll
                    for (int ds = 0; ds < 4; ++ds) acc[ds][r] *= fr;
                    accl[r] *= fr;
                }
            }

            #pragma unroll
            for (int cs = 0; cs < 4; ++cs)
                #pragma unroll
                for (int r = 0; r < 4; ++r)
                    s[cs][r] = fexp2(fmaf(s[cs][r], C2, -m));

            unsigned pk[4][2];
            #pragma unroll
            for (int cs = 0; cs < 4; ++cs) {
                pk[cs][0] = cvt_pk_bf16(s[cs][0], s[cs][1]);
                pk[cs][1] = cvt_pk_bf16(s[cs][2], s[cs][3]);
            }
            #pragma unroll
            for (int ks = 0; ks < 2; ++ks)
                #pragma unroll
                for (int i = 0; i < 2; ++i) {
#if HAVE_PERMLANE
                    auto r1 = __builtin_amdgcn_permlane32_swap(
                        pk[ks * 2][i], pk[ks * 2 + 1][i], false, false);
                    auto r2 = __builtin_amdgcn_permlane16_swap(r1[0], r1[1], false, false);
                    pf[ks].u[i]     = r2[0];
                    pf[ks].u[2 + i] = r2[1];
#else
                    const unsigned A  = pk[ks * 2][i];
                    const unsigned B  = pk[ks * 2 + 1][i];
                    const unsigned Ax = __shfl_xor(A, 32);
                    const unsigned Bx = __shfl_xor(B, 32);
                    const unsigned P1 = (l4 < 2) ? A : Bx;
                    const unsigned P2 = (l4 < 2) ? Ax : B;
                    const unsigned S1 = __shfl_xor(P1, 16);
                    const unsigned S2 = __shfl_xor(P2, 16);
                    pf[ks].u[i]     = (l4 & 1) ? S2 : P1;
                    pf[ks].u[2 + i] = (l4 & 1) ? P2 : S1;
#endif
                }
        };

        __syncthreads();          // protect K/V buffers from previous segment
        stage(0, 0);
        __syncthreads();

        int buf = 0;
        for (int kt = 0;;) {
            if (kt < ktmax) stage(buf ^ 1, kt + 1);   // async prefetch

            const unsigned short* Kb = Ks[buf];
            const unsigned short* Vb = Vs[buf];

            // ---- MFMA cluster: QK(kt) + deferred PV/rowsum(kt-1) ----
            f32x4 s[4] = {};
            __builtin_amdgcn_s_setprio(1);
            #pragma unroll
            for (int ks = 0; ks < 2; ++ks) {
                const bfrag qk = ks ? qf1 : qf0;
                #pragma unroll
                for (int cs = 0; cs < 4; ++cs) {
                    const int row = cs * 16 + l15;
                    const int ch  = (ks * 4 + l4) ^ (row & 7);
                    const bfrag kf = *(const bfrag*)(Kb + row * 64 + ch * 8);
                    s[cs] = __builtin_amdgcn_mfma_f32_16x16x32_bf16(kf, qk, s[cs], 0, 0, 0);
                }
            }
            #pragma unroll
            for (int ks = 0; ks < 2; ++ks) {
                #pragma unroll
                for (int ds = 0; ds < 4; ++ds)
                    acc[ds] = __builtin_amdgcn_mfma_f32_16x16x32_bf16(
                        pf[ks].f, vr[ks][ds], acc[ds], 0, 0, 0);
                accl = __builtin_amdgcn_mfma_f32_16x16x32_bf16(pf[ks].f, onesf, accl, 0, 0, 0);
            }
            __builtin_amdgcn_s_setprio(0);

            // ---- refill V regs with tile kt ----
            #pragma unroll
            for (int ks = 0; ks < 2; ++ks)
                #pragma unroll
                for (int ds = 0; ds < 4; ++ds) {
                    const int vrow = ds * 16 + l15;
                    const int vch  = (ks * 4 + l4) ^ (vrow & 7);
                    vr[ks][ds] = *(const bfrag*)(Vb + vrow * 64 + vch * 8);
                }

            // ---- causal mask on diagonal tile (k > q) ----
            if (kt == ktmax) {
                #pragma unroll
                for (int cs = 0; cs < 4; ++cs)
                    #pragma unroll
                    for (int r = 0; r < 4; ++r)
                        if (cs * 16 + l4 * 4 + r > wid * 16 + l15)
                            s[cs][r] = -3.0e38f;
            }

            softmax_dance(s);

            if (kt == ktmax) break;
            __syncthreads();      // drains own gload_lds + all waves done
            buf ^= 1; ++kt;
        }

        // ---- epilogue: deferred PV + rowsum of final tile ----
        #pragma unroll
        for (int ks = 0; ks < 2; ++ks) {
            #pragma unroll
            for (int ds = 0; ds < 4; ++ds)
                acc[ds] = __builtin_amdgcn_mfma_f32_16x16x32_bf16(
                    pf[ks].f, vr[ks][ds], acc[ds], 0, 0, 0);
            accl = __builtin_amdgcn_mfma_f32_16x16x32_bf16(pf[ks].f, onesf, accl, 0, 0, 0);
        }

        // ---- normalize + store (accl rows match acc rows) ----
        #pragma unroll
        for (int r = 0; r < 4; ++r) {
            const float iv = 1.f / accl[r];
            unsigned short* o =
                yatt + (size_t)(b * SEQ + q0 + wid * 16 + l4 * 4 + r) * BDIM + h * HDIM;
            #pragma unroll
            for (int ds = 0; ds < 4; ++ds)
                o[ds * 16 + l15] = f2bf(acc[ds][r] * iv);
        }
    }
}

// ---------------- launch -----------------------------------------------------
extern "C" void kernel_launch(void* const* d_in, const int* in_sizes, int n_in,
                              void* d_out, int out_size, void* d_ws, size_t ws_size,
                              hipStream_t stream)
{
    const float* x      = (const float*)d_in[0];
    const float* w_qkv  = (const float*)d_in[1];
    const float* b_qkv  = (const float*)d_in[2];
    const float* w_proj = (const float*)d_in[3];
    const float* b_proj = (const float*)d_in[4];
    float* out = (float*)d_out;

    unsigned short* xb   = (unsigned short*)d_ws;                 // [8192][768]
    unsigned short* qb   = xb  + (size_t)MTOT * BDIM;             // [8192][768]
    unsigned short* kbuf = qb  + (size_t)MTOT * BDIM;             // [8192][768]
    unsigned short* vT   = kbuf + (size_t)MTOT * BDIM;            // [4*768][2048]
    unsigned short* yatt = vT  + (size_t)MTOT * BDIM;             // [8192][768]
    unsigned short* wqT  = yatt + (size_t)MTOT * BDIM;            // [2304][768]
    unsigned short* wpT  = wqT + (size_t)3 * BDIM * BDIM;         // [768][768]

    // fused prep (x conv + both weight transposes)
    prep_all<<<dim3(3648), 256, 0, stream>>>(
        x, xb, w_qkv, wqT, w_proj, wpT);

    // qkv GEMM, 64x128 tiles (grid 18x128 = 2304 blocks)
    gemm_qkv<<<dim3(18, 128), 256, 0, stream>>>(
        xb, wqT, b_qkv, qb, kbuf, vT);

    // flash attention (768 uniform static causal-paired items, 3 blocks/CU)
    attn_flash_mfma<<<dim3(768), 256, 0, stream>>>(qb, kbuf, vT, yatt);

    // out = yatt @ w_proj + b_proj   (fp32 out, 64x128 tiles)
    gemm_proj<<<dim3(BDIM / 128, MTOT / 64), 256, 0, stream>>>(
        yatt, wpT, b_proj, out);
}